// Round 1
// baseline (824.765 us; speedup 1.0000x reference)
//
#include <hip/hip_runtime.h>
#include <math.h>

#define EPSF 1e-6f
#define THR 0.5f
#define PUSH_W 1.0f
#define PULL_W 1.0f

constexpr int BN = 2048;   // proposals per batch
constexpr int BG = 64;     // gt boxes per batch
constexpr int NT = 256;    // threads per block
constexpr int PT = BN / NT; // 8 elements per thread
constexpr int NW = NT / 64; // 4 waves

__global__ __launch_bounds__(NT) void nms_loss_kernel(
    const int* __restrict__ gti_all,    // B*N
    const float* __restrict__ gtb_all,  // B*G*4
    const float* __restrict__ prop_all, // B*N*5
    float* __restrict__ out_bp)         // B*2 (push, pull)
{
  const int b = blockIdx.x;
  const int tid = threadIdx.x;
  const int lane = tid & 63;
  const int wave = tid >> 6;

  __shared__ float4 box[BN];          // 32 KB
  __shared__ float sc[BN];            // 8 KB
  __shared__ float per[BN];           // 8 KB
  __shared__ int gts[BN];             // 8 KB
  __shared__ unsigned char act[BN];   // 2 KB
  __shared__ int rec[BG];
  __shared__ float rs[NW];
  __shared__ int ri[NW];
  __shared__ int rrem[NW];
  __shared__ int rqc[NW];
  __shared__ float rqs[NW];
  __shared__ int rany[NW];
  __shared__ int sh_nact;
  __shared__ int sh_i;
  __shared__ int sh_ig;
  __shared__ float4 sh_ibox;

  const int* gti = gti_all + b * BN;
  const float* GB = gtb_all + b * BG * 4;
  const float* P = prop_all + (size_t)b * BN * 5;

  // ---- precompute: stage boxes/scores, per[j], active init, rec init ----
  int local_pos = 0;
  for (int k = 0; k < PT; ++k) {
    int j = tid + k * NT;
    float x1 = P[j * 5 + 0], y1 = P[j * 5 + 1];
    float x2 = P[j * 5 + 2], y2 = P[j * 5 + 3];
    float s  = P[j * 5 + 4];
    box[j] = make_float4(x1, y1, x2, y2);
    sc[j] = s;
    int g = gti[j];
    gts[j] = g;
    unsigned char a = (g >= 0) ? 1 : 0;
    act[j] = a;
    local_pos += a;
    float pv = 0.f;
    if (g >= 0) {
      float gx1 = GB[g * 4 + 0], gy1 = GB[g * 4 + 1];
      float gx2 = GB[g * 4 + 2], gy2 = GB[g * 4 + 3];
      float aa = (gx2 - gx1) * (gy2 - gy1);
      float ab = (x2 - x1) * (y2 - y1);
      float w = fmaxf(fminf(gx2, x2) - fmaxf(gx1, x1), 0.f);
      float h = fmaxf(fminf(gy2, y2) - fmaxf(gy1, y1), 0.f);
      float inter = w * h;
      float iou = inter / (aa + ab - inter + EPSF);
      pv = -logf(EPSF + iou) * s;   // per[j] = -log(EPS+gpi_per)*score
    }
    per[j] = pv;
  }
  if (tid < BG) rec[tid] = -1;
  for (int off = 32; off; off >>= 1) local_pos += __shfl_down(local_pos, off);
  if (lane == 0) rrem[wave] = local_pos;
  __syncthreads();
  int n_pos = 0;               // only meaningful on tid==0
  if (tid == 0) {
    for (int w = 0; w < NW; ++w) n_pos += rrem[w];
    sh_nact = n_pos;
  }
  // thread-0 accumulators
  float pull_sum = 0.f, push_sum = 0.f, pull_cnt = 0.f, push_cnt = 0.f;
  int t0_hasrem = 0;
  __syncthreads();

  // ---- sequential greedy scan (early-exit when active set empties) ----
  while (true) {
    int nact = sh_nact;
    if (nact <= 0) break;

    // phase A: argmax over active scores; ties -> min index (jnp.argmax)
    float bs = -INFINITY;
    int bi = BN;
    for (int k = 0; k < PT; ++k) {
      int j = tid + k * NT;
      if (act[j]) {
        float s = sc[j];
        if (s > bs || (s == bs && j < bi)) { bs = s; bi = j; }
      }
    }
    for (int off = 32; off; off >>= 1) {
      float os = __shfl_down(bs, off);
      int   oi = __shfl_down(bi, off);
      if (os > bs || (os == bs && oi < bi)) { bs = os; bi = oi; }
    }
    if (lane == 0) { rs[wave] = bs; ri[wave] = bi; }
    __syncthreads();

    if (tid == 0) {
      float cs = rs[0]; int ci = ri[0];
      for (int w = 1; w < NW; ++w) {
        if (rs[w] > cs || (rs[w] == cs && ri[w] < ci)) { cs = rs[w]; ci = ri[w]; }
      }
      int i = ci;
      int ig = gts[i];
      act[i] = 0;
      int nrem = nact - 1;
      t0_hasrem = (nrem > 0);
      int r = rec[ig];
      if (r >= 0) {                    // seen
        pull_cnt += 1.f;               // counted even when !has_rem
        if (t0_hasrem) {
          float4 br = box[r]; float4 bb = box[i];
          float ar = (br.z - br.x) * (br.w - br.y);
          float ai = (bb.z - bb.x) * (bb.w - bb.y);
          float w = fmaxf(fminf(br.z, bb.z) - fmaxf(br.x, bb.x), 0.f);
          float h = fmaxf(fminf(br.w, bb.w) - fmaxf(br.y, bb.y), 0.f);
          float inter = w * h;
          float iou = inter / (ar + ai - inter + EPSF);
          float m = fmaxf(iou, EPSF);
          pull_sum += -logf(1.f - THR + m) * sc[i];
        }
      } else {
        rec[ig] = i;                   // first pick for this gt
      }
      sh_i = i; sh_ig = ig; sh_ibox = box[i];
    }
    __syncthreads();

    // phase B: suppress overlaps of picked box, gather push candidates
    float4 ib = sh_ibox;
    int ig = sh_ig;
    float iarea = (ib.z - ib.x) * (ib.w - ib.y);
    int removed = 0, qc = 0, anyp = 0;
    float qs = 0.f;
    for (int k = 0; k < PT; ++k) {
      int j = tid + k * NT;
      if (act[j]) {                    // act[i] already cleared => rem
        float4 bj = box[j];
        float ja = (bj.z - bj.x) * (bj.w - bj.y);
        float w = fmaxf(fminf(ib.z, bj.z) - fmaxf(ib.x, bj.x), 0.f);
        float h = fmaxf(fminf(ib.w, bj.w) - fmaxf(ib.y, bj.y), 0.f);
        float inter = w * h;
        float iou = inter / (iarea + ja - inter + EPSF);
        if (iou > THR) {               // overlap
          act[j] = 0;
          removed++;
          int gj = gts[j];
          if (gj != ig) {              // push_mask
            anyp = 1;
            if (rec[gj] < 0) {         // q = push_mask & ~seen_s
              qc++;
              qs += per[j];
            }
          }
        }
      }
    }
    for (int off = 32; off; off >>= 1) {
      removed += __shfl_down(removed, off);
      qc      += __shfl_down(qc, off);
      qs      += __shfl_down(qs, off);
      anyp    |= __shfl_down(anyp, off);
    }
    if (lane == 0) { rrem[wave] = removed; rqc[wave] = qc; rqs[wave] = qs; rany[wave] = anyp; }
    __syncthreads();

    if (tid == 0) {
      int rm = 0, qct = 0, ap = 0; float qst = 0.f;
      for (int w = 0; w < NW; ++w) { rm += rrem[w]; qct += rqc[w]; qst += rqs[w]; ap |= rany[w]; }
      sh_nact = nact - 1 - rm;
      if (t0_hasrem && ap) {           // body_valid & has_push
        push_sum += qst / ((float)qct + EPSF);
        push_cnt += 1.f;
      }
    }
    __syncthreads();
  }

  if (tid == 0) {
    float gate = (n_pos > 1) ? 1.f : 0.f;
    out_bp[b * 2 + 0] = gate * push_sum / (push_cnt + EPSF);
    out_bp[b * 2 + 1] = gate * pull_sum / (pull_cnt + EPSF);
  }
}

__global__ void nms_finalize_kernel(const float* __restrict__ bp, float* __restrict__ out, int nb) {
  if (threadIdx.x == 0 && blockIdx.x == 0) {
    float ps = 0.f, pl = 0.f;
    for (int b = 0; b < nb; ++b) { ps += bp[2 * b]; pl += bp[2 * b + 1]; }
    float inv = 1.f / (float)nb;
    out[0] = ps * inv * PUSH_W;
    out[1] = pl * inv * PULL_W;
  }
}

extern "C" void kernel_launch(void* const* d_in, const int* in_sizes, int n_in,
                              void* d_out, int out_size, void* d_ws, size_t ws_size,
                              hipStream_t stream) {
  // inputs: gt_inds (B*N i32), anchor_gt_inds (B*N i32), gt_bboxes (B*G*4 f32),
  //         proposal_list (B*N*5 f32)
  const int* gti = (const int*)d_in[1];       // anchor_gt_inds (== gt_inds)
  const float* gtb = (const float*)d_in[2];
  const float* props = (const float*)d_in[3];
  float* out = (float*)d_out;
  float* bp = (float*)d_ws;                   // B*2 floats scratch

  const int nb = in_sizes[1] / BN;            // B = 8

  nms_loss_kernel<<<nb, NT, 0, stream>>>(gti, gtb, props, bp);
  nms_finalize_kernel<<<1, 64, 0, stream>>>(bp, out, nb);
}

// Round 2
// 242.664 us; speedup vs baseline: 3.3988x; 3.3988x over previous
//
#include <hip/hip_runtime.h>
#include <hip/hip_fp16.h>
#include <math.h>

#define EPSF 1e-6f
#define THR 0.5f
#define PUSH_W 1.0f
#define PULL_W 1.0f

constexpr int BN = 2048;    // proposals per batch
constexpr int BG = 64;      // gt boxes per batch

__device__ __forceinline__ float iou_box(float4 a, float4 b) {
  float aa = (a.z - a.x) * (a.w - a.y);
  float ab = (b.z - b.x) * (b.w - b.y);
  float w = fmaxf(fminf(a.z, b.z) - fmaxf(a.x, b.x), 0.f);
  float h = fmaxf(fminf(a.w, b.w) - fmaxf(a.y, b.y), 0.f);
  float inter = w * h;
  return inter / (aa + ab - inter + EPSF);
}

// ---------------------------------------------------------------- K1: sort
// Sort each batch's proposals by (score desc, idx asc) via u64-key bitonic.
// Write sorted box/per/gts/score arrays + per-GT rank bitmask to ws.
__global__ __launch_bounds__(256) void k1_sort(
    const int* __restrict__ gti_all, const float* __restrict__ gtb_all,
    const float* __restrict__ prop_all,
    float4* __restrict__ boxs, float* __restrict__ pers,
    int* __restrict__ gtss, float* __restrict__ scs,
    unsigned* __restrict__ gmask_g)
{
  const int b = blockIdx.x;
  const int tid = threadIdx.x;
  __shared__ unsigned long long key[BN];   // 16 KB
  __shared__ unsigned gm[BG * 64];         // 16 KB

  const float* P = prop_all + (size_t)b * BN * 5;
  const int* gti = gti_all + b * BN;
  const float* GB = gtb_all + b * BG * 4;

  for (int k = 0; k < 8; ++k) {
    int j = tid + k * 256;
    unsigned bits = __float_as_uint(P[j * 5 + 4]);
    key[j] = ((unsigned long long)bits << 32) | (unsigned)(BN - 1 - j);
  }
  __syncthreads();

  // bitonic, descending by key
  for (int k = 2; k <= BN; k <<= 1) {
    for (int jj = k >> 1; jj > 0; jj >>= 1) {
#pragma unroll
      for (int t = 0; t < 8; ++t) {
        int i = tid + t * 256;
        int p = i ^ jj;
        if (p > i) {
          bool up = ((i & k) == 0);
          unsigned long long a = key[i], c = key[p];
          bool sw = up ? (a < c) : (a > c);
          if (sw) { key[i] = c; key[p] = a; }
        }
      }
      __syncthreads();
    }
  }

  for (int k = 0; k < 16; ++k) gm[tid + k * 256] = 0u;
  __syncthreads();

  for (int t = 0; t < 8; ++t) {
    int r = tid + t * 256;
    unsigned long long kk = key[r];
    int idx = (BN - 1) - (int)(kk & 0xffffffffu);
    float x1 = P[idx * 5 + 0], y1 = P[idx * 5 + 1];
    float x2 = P[idx * 5 + 2], y2 = P[idx * 5 + 3], s = P[idx * 5 + 4];
    int g = gti[idx];
    float4 bx = make_float4(x1, y1, x2, y2);
    boxs[b * BN + r] = bx;
    scs[b * BN + r] = s;
    gtss[b * BN + r] = g;
    float pv = 0.f;
    if (g >= 0) {
      float4 gb = make_float4(GB[g * 4 + 0], GB[g * 4 + 1], GB[g * 4 + 2], GB[g * 4 + 3]);
      float i2 = iou_box(gb, bx);
      pv = -logf(EPSF + i2) * s;
      atomicOr(&gm[g * 64 + (r >> 5)], 1u << (r & 31));
    }
    pers[b * BN + r] = pv;
  }
  __syncthreads();
  for (int k = 0; k < 16; ++k) {
    int w = tid + k * 256;
    gmask_g[b * (BG * 64) + w] = gm[w];
  }
}

// ------------------------------------------------------------- K2: adjacency
// adj[b][i][w] (u32): bit j' set iff IoU(box_s[i], box_s[w*32+j']) > THR.
__global__ __launch_bounds__(256) void k2_adj(
    const float4* __restrict__ boxs, unsigned* __restrict__ adj)
{
  const int blk = blockIdx.x;   // 8 batches * 32 row-groups
  const int b = blk >> 5;
  const int rg = blk & 31;
  const int tid = threadIdx.x;
  __shared__ float4 bs[BN];     // 32 KB

  const float4* B = boxs + b * BN;
  for (int k = 0; k < 8; ++k) bs[tid + k * 256] = B[tid + k * 256];
  __syncthreads();

  const int row = rg * 64 + (tid >> 2);
  const int q = tid & 3;
  float4 rb = bs[row];
  unsigned* arow = adj + ((size_t)b * BN + row) * 64;
#pragma unroll
  for (int wi = 0; wi < 16; ++wi) {
    int w = q * 16 + wi;
    int j0 = w * 32;
    unsigned bits = 0;
#pragma unroll
    for (int jj = 0; jj < 32; ++jj) {
      float i2 = iou_box(rb, bs[j0 + jj]);
      bits |= (i2 > THR) ? (1u << jj) : 0u;
    }
    arow[w] = bits;
  }
}

// ------------------------------------------------------------------ K3: scan
// One wave per batch. act/unseen masks: lane l owns ranks [l*32, l*32+32).
__global__ __launch_bounds__(64) void k3_scan(
    const float4* __restrict__ boxs_g, const float* __restrict__ pers_g,
    const int* __restrict__ gtss_g, const float* __restrict__ scs_g,
    const unsigned* __restrict__ gmask_g, const unsigned* __restrict__ adj,
    float* __restrict__ out_bp)
{
  const int b = blockIdx.x;
  const int lane = threadIdx.x;   // 0..63

  __shared__ float4 box[BN];          // 32 KB
  __shared__ float per[BN];           // 8 KB
  __shared__ __half sch[BN];          // 4 KB
  __shared__ unsigned char gtsb[BN];  // 2 KB
  __shared__ unsigned gmask[BG * 64]; // 16 KB  -> 62 KB total

  // stage
  for (int k = 0; k < 32; ++k) {
    int j = lane + k * 64;
    box[j] = boxs_g[b * BN + j];
  }
  for (int k = 0; k < 32; ++k) {
    int j = lane + k * 64;
    per[j] = pers_g[b * BN + j];
    sch[j] = __float2half(scs_g[b * BN + j]);
  }
  for (int k = 0; k < 64; ++k) {
    int j = lane + k * 64;
    gmask[j] = gmask_g[b * (BG * 64) + j];
  }
  unsigned act = 0;
  for (int k = 0; k < 32; ++k) {
    int r = (lane << 5) + k;
    int g = gtss_g[b * BN + r];
    gtsb[r] = (unsigned char)g;
    if (g >= 0) act |= (1u << k);
  }
  __syncthreads();

  float npos = (float)__popc(act);
  for (int o = 1; o < 64; o <<= 1) npos += __shfl_xor(npos, o);

  unsigned unseen = 0xffffffffu;
  int rec = -1;                       // lane l holds rec for GT l
  float pull_sum = 0.f, pull_cnt = 0.f, push_sum = 0.f, push_cnt = 0.f;
  const unsigned* A = adj + (size_t)b * BN * 64;

  // prologue: first pick + row load
  int i = -1;
  unsigned row = 0;
  {
    unsigned long long bal = __ballot(act != 0);
    if (bal) {
      int L = (int)__ffsll((unsigned long long)bal) - 1;
      unsigned w0 = __shfl(act, L);
      i = (L << 5) + __ffs(w0) - 1;
      row = A[(size_t)i * 64 + lane];
    }
  }

  while (i >= 0) {
    // rem / suppression (waits on row)
    unsigned rem = act;
    if (lane == (i >> 5)) rem &= ~(1u << (i & 31));
    bool has_rem = __any(rem != 0);
    unsigned actn = rem & ~row;

    // find next pick, issue its row load + warm 3 rows ahead
    int inext = -1;
    unsigned rown = 0;
    {
      unsigned long long bal = __ballot(actn != 0);
      if (bal) {
        int L = (int)__ffsll((unsigned long long)bal) - 1;
        unsigned w0 = __shfl(actn, L);
        inext = (L << 5) + __ffs(w0) - 1;
        rown = A[(size_t)inext * 64 + lane];
        int w1 = inext + 1 < BN ? inext + 1 : BN - 1;
        int w2 = inext + 2 < BN ? inext + 2 : BN - 1;
        int w3 = inext + 3 < BN ? inext + 3 : BN - 1;
        unsigned t1 = A[(size_t)w1 * 64 + lane];
        unsigned t2 = A[(size_t)w2 * 64 + lane];
        unsigned t3 = A[(size_t)w3 * 64 + lane];
        asm volatile("" :: "v"(t1), "v"(t2), "v"(t3));  // keep warms live
      }
    }

    // bookkeeping for pick i (overlaps rown flight)
    int ig = (int)gtsb[i];
    int r_old = __shfl(rec, ig);
    bool seen = r_old >= 0;
    if (seen) {
      pull_cnt += 1.f;
      if (has_rem) {
        float i2 = iou_box(box[r_old], box[i]);
        float m = fmaxf(i2, EPSF);
        pull_sum += -logf(1.f - THR + m) * __half2float(sch[i]);
      }
    }
    unsigned gm = gmask[(ig << 6) + lane];
    unsigned ovl = row & rem;
    unsigned p_w = ovl & ~gm;
    bool has_push = __any(p_w != 0);
    if (!seen) {
      if (lane == ig) rec = i;
      unseen &= ~gm;                 // GT ig becomes seen BEFORE q eval
    }
    if (has_rem && has_push) {
      unsigned q_w = p_w & unseen;
      float qc = (float)__popc(q_w);
      float qs = 0.f;
      while (q_w) {
        int bb = __ffs(q_w) - 1;
        q_w &= q_w - 1;
        qs += per[(lane << 5) + bb];
      }
      for (int o = 1; o < 64; o <<= 1) {
        qs += __shfl_xor(qs, o);
        qc += __shfl_xor(qc, o);
      }
      push_sum += qs / (qc + EPSF);
      push_cnt += 1.f;
    }

    act = actn;
    i = inext;
    row = rown;
  }

  if (lane == 0) {
    float gate = (npos > 1.f) ? 1.f : 0.f;
    out_bp[b * 2 + 0] = gate * push_sum / (push_cnt + EPSF);
    out_bp[b * 2 + 1] = gate * pull_sum / (pull_cnt + EPSF);
  }
}

__global__ void nms_finalize_kernel(const float* __restrict__ bp, float* __restrict__ out, int nb) {
  if (threadIdx.x == 0 && blockIdx.x == 0) {
    float ps = 0.f, pl = 0.f;
    for (int b = 0; b < nb; ++b) { ps += bp[2 * b]; pl += bp[2 * b + 1]; }
    float inv = 1.f / (float)nb;
    out[0] = ps * inv * PUSH_W;
    out[1] = pl * inv * PULL_W;
  }
}

// =============================== fallback path (round-1 kernel, proven) =====
constexpr int NT = 256;
constexpr int PT = BN / NT;
constexpr int NW = NT / 64;

__global__ __launch_bounds__(NT) void nms_loss_kernel(
    const int* __restrict__ gti_all, const float* __restrict__ gtb_all,
    const float* __restrict__ prop_all, float* __restrict__ out_bp)
{
  const int b = blockIdx.x;
  const int tid = threadIdx.x;
  const int lane = tid & 63;
  const int wave = tid >> 6;

  __shared__ float4 box[BN];
  __shared__ float sc[BN];
  __shared__ float per[BN];
  __shared__ int gts[BN];
  __shared__ unsigned char act[BN];
  __shared__ int rec[BG];
  __shared__ float rs[NW];
  __shared__ int ri[NW];
  __shared__ int rrem[NW];
  __shared__ int rqc[NW];
  __shared__ float rqs[NW];
  __shared__ int rany[NW];
  __shared__ int sh_nact;
  __shared__ int sh_ig;
  __shared__ float4 sh_ibox;

  const int* gti = gti_all + b * BN;
  const float* GB = gtb_all + b * BG * 4;
  const float* P = prop_all + (size_t)b * BN * 5;

  int local_pos = 0;
  for (int k = 0; k < PT; ++k) {
    int j = tid + k * NT;
    float x1 = P[j * 5 + 0], y1 = P[j * 5 + 1];
    float x2 = P[j * 5 + 2], y2 = P[j * 5 + 3];
    float s = P[j * 5 + 4];
    box[j] = make_float4(x1, y1, x2, y2);
    sc[j] = s;
    int g = gti[j];
    gts[j] = g;
    unsigned char a = (g >= 0) ? 1 : 0;
    act[j] = a;
    local_pos += a;
    float pv = 0.f;
    if (g >= 0) {
      float4 gb = make_float4(GB[g * 4], GB[g * 4 + 1], GB[g * 4 + 2], GB[g * 4 + 3]);
      float i2 = iou_box(gb, make_float4(x1, y1, x2, y2));
      pv = -logf(EPSF + i2) * s;
    }
    per[j] = pv;
  }
  if (tid < BG) rec[tid] = -1;
  for (int off = 32; off; off >>= 1) local_pos += __shfl_down(local_pos, off);
  if (lane == 0) rrem[wave] = local_pos;
  __syncthreads();
  int n_pos = 0;
  if (tid == 0) {
    for (int w = 0; w < NW; ++w) n_pos += rrem[w];
    sh_nact = n_pos;
  }
  float pull_sum = 0.f, push_sum = 0.f, pull_cnt = 0.f, push_cnt = 0.f;
  int t0_hasrem = 0;
  __syncthreads();

  while (true) {
    int nact = sh_nact;
    if (nact <= 0) break;
    float bs = -INFINITY;
    int bi = BN;
    for (int k = 0; k < PT; ++k) {
      int j = tid + k * NT;
      if (act[j]) {
        float s = sc[j];
        if (s > bs || (s == bs && j < bi)) { bs = s; bi = j; }
      }
    }
    for (int off = 32; off; off >>= 1) {
      float os = __shfl_down(bs, off);
      int oi = __shfl_down(bi, off);
      if (os > bs || (os == bs && oi < bi)) { bs = os; bi = oi; }
    }
    if (lane == 0) { rs[wave] = bs; ri[wave] = bi; }
    __syncthreads();
    if (tid == 0) {
      float cs = rs[0]; int ci = ri[0];
      for (int w = 1; w < NW; ++w)
        if (rs[w] > cs || (rs[w] == cs && ri[w] < ci)) { cs = rs[w]; ci = ri[w]; }
      int i = ci;
      int ig = gts[i];
      act[i] = 0;
      t0_hasrem = (nact - 1 > 0);
      int r = rec[ig];
      if (r >= 0) {
        pull_cnt += 1.f;
        if (t0_hasrem) {
          float i2 = iou_box(box[r], box[i]);
          float m = fmaxf(i2, EPSF);
          pull_sum += -logf(1.f - THR + m) * sc[i];
        }
      } else {
        rec[ig] = i;
      }
      sh_ig = ig; sh_ibox = box[i];
    }
    __syncthreads();
    float4 ib = sh_ibox;
    int igx = sh_ig;
    int removed = 0, qc = 0, anyp = 0;
    float qs = 0.f;
    for (int k = 0; k < PT; ++k) {
      int j = tid + k * NT;
      if (act[j]) {
        float i2 = iou_box(ib, box[j]);
        if (i2 > THR) {
          act[j] = 0;
          removed++;
          int gj = gts[j];
          if (gj != igx) {
            anyp = 1;
            if (rec[gj] < 0) { qc++; qs += per[j]; }
          }
        }
      }
    }
    for (int off = 32; off; off >>= 1) {
      removed += __shfl_down(removed, off);
      qc += __shfl_down(qc, off);
      qs += __shfl_down(qs, off);
      anyp |= __shfl_down(anyp, off);
    }
    if (lane == 0) { rrem[wave] = removed; rqc[wave] = qc; rqs[wave] = qs; rany[wave] = anyp; }
    __syncthreads();
    if (tid == 0) {
      int rm = 0, qct = 0, ap = 0; float qst = 0.f;
      for (int w = 0; w < NW; ++w) { rm += rrem[w]; qct += rqc[w]; qst += rqs[w]; ap |= rany[w]; }
      sh_nact = nact - 1 - rm;
      if (t0_hasrem && ap) {
        push_sum += qst / ((float)qct + EPSF);
        push_cnt += 1.f;
      }
    }
    __syncthreads();
  }

  if (tid == 0) {
    float gate = (n_pos > 1) ? 1.f : 0.f;
    out_bp[b * 2 + 0] = gate * push_sum / (push_cnt + EPSF);
    out_bp[b * 2 + 1] = gate * pull_sum / (pull_cnt + EPSF);
  }
}

// ============================================================== launch =====
extern "C" void kernel_launch(void* const* d_in, const int* in_sizes, int n_in,
                              void* d_out, int out_size, void* d_ws, size_t ws_size,
                              hipStream_t stream) {
  const int* gti = (const int*)d_in[1];
  const float* gtb = (const float*)d_in[2];
  const float* props = (const float*)d_in[3];
  float* out = (float*)d_out;
  const int nb = in_sizes[1] / BN;   // 8

  // ws layout (bytes)
  const size_t off_adj  = 0;                       // nb*2048*64 u32 = 4 MB
  const size_t off_box  = off_adj  + (size_t)nb * BN * 64 * 4;
  const size_t off_per  = off_box  + (size_t)nb * BN * 16;
  const size_t off_gts  = off_per  + (size_t)nb * BN * 4;
  const size_t off_sc   = off_gts  + (size_t)nb * BN * 4;
  const size_t off_gm   = off_sc   + (size_t)nb * BN * 4;
  const size_t off_bp   = off_gm   + (size_t)nb * BG * 64 * 4;
  const size_t needed   = off_bp + (size_t)nb * 2 * 4;

  if (ws_size >= needed) {
    char* ws = (char*)d_ws;
    unsigned* adj = (unsigned*)(ws + off_adj);
    float4* boxs = (float4*)(ws + off_box);
    float* pers = (float*)(ws + off_per);
    int* gtss = (int*)(ws + off_gts);
    float* scs = (float*)(ws + off_sc);
    unsigned* gmask = (unsigned*)(ws + off_gm);
    float* bp = (float*)(ws + off_bp);

    k1_sort<<<nb, 256, 0, stream>>>(gti, gtb, props, boxs, pers, gtss, scs, gmask);
    k2_adj<<<nb * 32, 256, 0, stream>>>(boxs, adj);
    k3_scan<<<nb, 64, 0, stream>>>(boxs, pers, gtss, scs, gmask, adj, bp);
    nms_finalize_kernel<<<1, 64, 0, stream>>>(bp, out, nb);
  } else {
    float* bp = (float*)d_ws;
    nms_loss_kernel<<<nb, NT, 0, stream>>>(gti, gtb, props, bp);
    nms_finalize_kernel<<<1, 64, 0, stream>>>(bp, out, nb);
  }
}

// Round 3
// 162.115 us; speedup vs baseline: 5.0875x; 1.4969x over previous
//
#include <hip/hip_runtime.h>
#include <math.h>
#include <limits.h>

#define EPSF 1e-6f
#define THR 0.5f
#define PUSH_W 1.0f
#define PULL_W 1.0f

constexpr int BN = 2048;    // proposals per batch
constexpr int BG = 64;      // gt boxes per batch

__device__ __forceinline__ float iou_box(float4 a, float4 b) {
  float aa = (a.z - a.x) * (a.w - a.y);
  float ab = (b.z - b.x) * (b.w - b.y);
  float w = fmaxf(fminf(a.z, b.z) - fmaxf(a.x, b.x), 0.f);
  float h = fmaxf(fminf(a.w, b.w) - fmaxf(a.y, b.y), 0.f);
  float inter = w * h;
  return inter / (aa + ab - inter + EPSF);
}

// ---------------------------------------------------------------- K1: sort
__global__ __launch_bounds__(256) void k1_sort(
    const int* __restrict__ gti_all, const float* __restrict__ gtb_all,
    const float* __restrict__ prop_all,
    float4* __restrict__ boxs, float* __restrict__ pers,
    short* __restrict__ gtss, float* __restrict__ scs,
    unsigned* __restrict__ actw_g)
{
  const int b = blockIdx.x;
  const int tid = threadIdx.x;
  __shared__ unsigned long long key[BN];   // 16 KB
  __shared__ unsigned aw[64];

  const float* P = prop_all + (size_t)b * BN * 5;
  const int* gti = gti_all + b * BN;
  const float* GB = gtb_all + b * BG * 4;

  for (int k = 0; k < 8; ++k) {
    int j = tid + k * 256;
    unsigned bits = __float_as_uint(P[j * 5 + 4]);
    key[j] = ((unsigned long long)bits << 32) | (unsigned)(BN - 1 - j);
  }
  __syncthreads();

  for (int k = 2; k <= BN; k <<= 1) {
    for (int jj = k >> 1; jj > 0; jj >>= 1) {
#pragma unroll
      for (int t = 0; t < 8; ++t) {
        int i = tid + t * 256;
        int p = i ^ jj;
        if (p > i) {
          bool up = ((i & k) == 0);
          unsigned long long a = key[i], c = key[p];
          bool sw = up ? (a < c) : (a > c);
          if (sw) { key[i] = c; key[p] = a; }
        }
      }
      __syncthreads();
    }
  }

  if (tid < 64) aw[tid] = 0u;
  __syncthreads();

  for (int t = 0; t < 8; ++t) {
    int r = tid + t * 256;
    unsigned long long kk = key[r];
    int idx = (BN - 1) - (int)(kk & 0xffffffffu);
    float x1 = P[idx * 5 + 0], y1 = P[idx * 5 + 1];
    float x2 = P[idx * 5 + 2], y2 = P[idx * 5 + 3], s = P[idx * 5 + 4];
    int g = gti[idx];
    float4 bx = make_float4(x1, y1, x2, y2);
    boxs[b * BN + r] = bx;
    scs[b * BN + r] = s;
    gtss[b * BN + r] = (short)g;
    float pv = 0.f;
    if (g >= 0) {
      float4 gb = make_float4(GB[g * 4 + 0], GB[g * 4 + 1], GB[g * 4 + 2], GB[g * 4 + 3]);
      float i2 = iou_box(gb, bx);
      pv = -logf(EPSF + i2) * s;
      atomicOr(&aw[r >> 5], 1u << (r & 31));
    }
    pers[b * BN + r] = pv;
  }
  __syncthreads();
  if (tid < 64) actw_g[b * 64 + tid] = aw[tid];
}

// ------------------------------------------------------------- K2: adjacency
__global__ __launch_bounds__(256) void k2_adj(
    const float4* __restrict__ boxs, unsigned* __restrict__ adj)
{
  const int blk = blockIdx.x;   // 8 batches * 32 row-groups
  const int b = blk >> 5;
  const int rg = blk & 31;
  const int tid = threadIdx.x;
  __shared__ float4 bs[BN];     // 32 KB

  const float4* B = boxs + b * BN;
  for (int k = 0; k < 8; ++k) bs[tid + k * 256] = B[tid + k * 256];
  __syncthreads();

  const int row = rg * 64 + (tid >> 2);
  const int q = tid & 3;
  float4 rb = bs[row];
  unsigned* arow = adj + ((size_t)b * BN + row) * 64;
#pragma unroll
  for (int wi = 0; wi < 16; ++wi) {
    int w = q * 16 + wi;
    int j0 = w * 32;
    unsigned bits = 0;
#pragma unroll
    for (int jj = 0; jj < 32; ++jj) {
      float i2 = iou_box(rb, bs[j0 + jj]);
      bits |= (i2 > THR) ? (1u << jj) : 0u;
    }
    arow[w] = bits;
  }
}

// ------------------------------------------- K3: pick-resolve + parallel loss
__global__ __launch_bounds__(256) void k3_resolve_loss(
    const float4* __restrict__ boxs, const float* __restrict__ pers,
    const short* __restrict__ gtss, const float* __restrict__ scs,
    const unsigned* __restrict__ actw, const unsigned* __restrict__ adj,
    float* __restrict__ out_bp)
{
  const int b = blockIdx.x;
  const int tid = threadIdx.x;
  const int lane = tid & 63;
  const int wave = tid >> 6;

  __shared__ unsigned short plist[BN];   // pick ranks in order (4 KB)
  __shared__ unsigned pm_s[64];          // pickmask
  __shared__ unsigned pmpre[64];         // prefix popcounts
  __shared__ short gts_s[BN];            // 4 KB
  __shared__ float qs[BN];               // 8 KB
  __shared__ int qc[BN];                 // 8 KB
  __shared__ unsigned hp[64];            // has_push bit per event
  __shared__ int fpr[BG];                // first pick rank per GT
  __shared__ unsigned short ev2rank[BN]; // 4 KB
  __shared__ int Pcnt, lastrem, nposs;
  __shared__ float redp[4][4];

  const unsigned* A = adj + (size_t)b * BN * 64;

  // ---- phase A: init accumulators, stage gts ----
  int myp = 0;
  for (int k = 0; k < 8; ++k) {
    int j = tid + k * 256;
    qs[j] = 0.f; qc[j] = 0;
    short g = gtss[b * BN + j];
    gts_s[j] = g;
    myp += (g >= 0) ? 1 : 0;
  }
  if (tid < 64) { hp[tid] = 0u; fpr[tid] = INT_MAX; }
  if (tid == 0) { Pcnt = 0; lastrem = 0; nposs = 0; }
  for (int o = 1; o < 64; o <<= 1) myp += __shfl_xor(myp, o);
  __syncthreads();
  if (lane == 0) atomicAdd(&nposs, myp);
  __syncthreads();

  // ---- phase B: wave0 greedy resolve over 32 chunks of 64 ranks ----
  if (wave == 0) {
    unsigned sup = 0;
    unsigned act = actw[b * 64 + lane];
    unsigned mypm = 0;
    int npick = 0;                 // wave-uniform
    int prevbase = 0, prevcnt = 0;
    uint2 diag = *(const uint2*)&A[(size_t)lane * 64 + 0];   // chunk 0
    for (int c = 0; c < 32; ++c) {
      // prefetch next chunk's symmetric diag block (row lane == col lane)
      uint2 diagn = diag;
      if (c + 1 < 32)
        diagn = *(const uint2*)&A[(size_t)((c + 1) * 64 + lane) * 64 + 2 * (c + 1)];

      // apply previous chunk's picks to sup (16-wide batched loads)
      for (int t = 0; t < prevcnt; t += 16) {
        unsigned r[16];
#pragma unroll
        for (int k = 0; k < 16; ++k) {
          int idx = prevbase + t + k;
          int lim = prevbase + prevcnt - 1;
          if (idx > lim) idx = lim;
          int rank = (int)plist[idx];
          r[k] = A[(size_t)rank * 64 + lane];
        }
        unsigned acc = 0;
#pragma unroll
        for (int k = 0; k < 16; ++k) acc |= r[k];
        sup |= acc;
      }

      // per-lane candidate bit for this chunk
      unsigned as0 = act & ~sup;
      unsigned w0 = (unsigned)__shfl((int)as0, 2 * c);
      unsigned w1 = (unsigned)__shfl((int)as0, 2 * c + 1);
      unsigned mybit = (lane < 32) ? ((w0 >> lane) & 1u) : ((w1 >> (lane - 32)) & 1u);

      unsigned long long myrow = ((unsigned long long)diag.y << 32) | (unsigned long long)diag.x;
      unsigned long long pickword = 0;
      int cbase = npick;
      while (true) {
        unsigned long long bal = __ballot(mybit != 0u);
        if (!bal) break;
        int bpos = (int)__ffsll(bal) - 1;
        pickword |= (1ull << bpos);
        if (lane == 0) plist[npick] = (unsigned short)(c * 64 + bpos);
        npick++;
        mybit &= ~((unsigned)((myrow >> bpos) & 1ull));  // symmetric: my row bit bpos == col bit
      }
      if (lane == 2 * c)     mypm |= (unsigned)(pickword & 0xffffffffull);
      if (lane == 2 * c + 1) mypm |= (unsigned)(pickword >> 32);
      prevbase = cbase; prevcnt = npick - cbase;
      diag = diagn;
    }
    pm_s[lane] = mypm;
    if (lane == 0) Pcnt = npick;
  }
  __syncthreads();

  // ---- phase C: prefix popcounts ----
  if (tid < 64) {
    int s = 0;
    for (int w = 0; w < tid; ++w) s += __popc(pm_s[w]);
    pmpre[tid] = (unsigned)s;
  }
  __syncthreads();

  const int P = Pcnt;

  // ---- stage 1: per-box removal event; picks fill ev2rank/fpr ----
  int rpv[8]; int ejv[8];
#pragma unroll
  for (int k = 0; k < 8; ++k) {
    int j = tid + (k << 8);
    const uint4* R = (const uint4*)(A + (size_t)j * 64);
    int frank = -1;
#pragma unroll
    for (int q = 0; q < 16; ++q) {
      uint4 r4 = R[q];
      unsigned m0 = r4.x & pm_s[q * 4 + 0];
      unsigned m1 = r4.y & pm_s[q * 4 + 1];
      unsigned m2 = r4.z & pm_s[q * 4 + 2];
      unsigned m3 = r4.w & pm_s[q * 4 + 3];
      if (frank < 0 && m0) frank = q * 128 +  0 + __ffs(m0) - 1;
      if (frank < 0 && m1) frank = q * 128 + 32 + __ffs(m1) - 1;
      if (frank < 0 && m2) frank = q * 128 + 64 + __ffs(m2) - 1;
      if (frank < 0 && m3) frank = q * 128 + 96 + __ffs(m3) - 1;
    }
    int e = -1;
    if (frank >= 0)
      e = (int)pmpre[frank >> 5] + __popc(pm_s[frank >> 5] & ((1u << (frank & 31)) - 1u));
    rpv[k] = frank; ejv[k] = e;
    if (frank == j) {                       // j is a pick
      ev2rank[e] = (unsigned short)j;
      atomicMin(&fpr[(int)gts_s[j]], j);
      rpv[k] = -1;                          // no removal contribution
    }
  }
  __syncthreads();

  // ---- stage 2: non-pick removal contributions (fpr now final) ----
#pragma unroll
  for (int k = 0; k < 8; ++k) {
    int j = tid + (k << 8);
    int frank = rpv[k];
    if (frank < 0) continue;
    int gj = (int)gts_s[j];
    if (gj < 0) continue;                   // never active
    int e = ejv[k];
    if (e == P - 1) atomicOr(&lastrem, 1);
    int gt = (int)gts_s[frank];
    if (gj != gt) {
      atomicOr(&hp[e >> 5], 1u << (e & 31));
      if (fpr[gj] > frank) {                // unseen at event e (post-update rec)
        atomicAdd(&qs[e], pers[b * BN + j]);
        atomicAdd(&qc[e], 1);
      }
    }
  }
  __syncthreads();

  // ---- event pass: pull/push per event, block reduce ----
  float pull_l = 0.f, pcl = 0.f, push_l = 0.f, pshl = 0.f;
  for (int t = tid; t < P; t += 256) {
    int r = (int)ev2rank[t];
    int g = (int)gts_s[r];
    bool seen = (fpr[g] < r);
    bool hr = (t < P - 1) || (lastrem != 0);
    if (seen) {
      pcl += 1.f;
      if (hr) {
        float4 bA = boxs[b * BN + fpr[g]];
        float4 bB = boxs[b * BN + r];
        float io = iou_box(bA, bB);
        pull_l += -logf(1.f - THR + fmaxf(io, EPSF)) * scs[b * BN + r];
      }
    }
    if (hr && ((hp[t >> 5] >> (t & 31)) & 1u)) {
      pshl += 1.f;
      push_l += qs[t] / ((float)qc[t] + EPSF);
    }
  }
  for (int o = 1; o < 64; o <<= 1) {
    pull_l += __shfl_xor(pull_l, o);
    pcl    += __shfl_xor(pcl, o);
    push_l += __shfl_xor(push_l, o);
    pshl   += __shfl_xor(pshl, o);
  }
  if (lane == 0) { redp[wave][0] = pull_l; redp[wave][1] = pcl; redp[wave][2] = push_l; redp[wave][3] = pshl; }
  __syncthreads();
  if (tid == 0) {
    float Ps = 0.f, Pc = 0.f, Ss = 0.f, Sc = 0.f;
    for (int w = 0; w < 4; ++w) { Ps += redp[w][0]; Pc += redp[w][1]; Ss += redp[w][2]; Sc += redp[w][3]; }
    float gate = (nposs > 1) ? 1.f : 0.f;
    out_bp[b * 2 + 0] = gate * Ss / (Sc + EPSF);   // push
    out_bp[b * 2 + 1] = gate * Ps / (Pc + EPSF);   // pull
  }
}

__global__ void nms_finalize_kernel(const float* __restrict__ bp, float* __restrict__ out, int nb) {
  if (threadIdx.x == 0 && blockIdx.x == 0) {
    float ps = 0.f, pl = 0.f;
    for (int b = 0; b < nb; ++b) { ps += bp[2 * b]; pl += bp[2 * b + 1]; }
    float inv = 1.f / (float)nb;
    out[0] = ps * inv * PUSH_W;
    out[1] = pl * inv * PULL_W;
  }
}

// =============================== fallback path (round-1 kernel, proven) =====
constexpr int NT = 256;
constexpr int PT = BN / NT;
constexpr int NW = NT / 64;

__global__ __launch_bounds__(NT) void nms_loss_kernel(
    const int* __restrict__ gti_all, const float* __restrict__ gtb_all,
    const float* __restrict__ prop_all, float* __restrict__ out_bp)
{
  const int b = blockIdx.x;
  const int tid = threadIdx.x;
  const int lane = tid & 63;
  const int wave = tid >> 6;

  __shared__ float4 box[BN];
  __shared__ float sc[BN];
  __shared__ float per[BN];
  __shared__ int gts[BN];
  __shared__ unsigned char act[BN];
  __shared__ int rec[BG];
  __shared__ float rs[NW];
  __shared__ int ri[NW];
  __shared__ int rrem[NW];
  __shared__ int rqc[NW];
  __shared__ float rqs[NW];
  __shared__ int rany[NW];
  __shared__ int sh_nact;
  __shared__ int sh_ig;
  __shared__ float4 sh_ibox;

  const int* gti = gti_all + b * BN;
  const float* GB = gtb_all + b * BG * 4;
  const float* P = prop_all + (size_t)b * BN * 5;

  int local_pos = 0;
  for (int k = 0; k < PT; ++k) {
    int j = tid + k * NT;
    float x1 = P[j * 5 + 0], y1 = P[j * 5 + 1];
    float x2 = P[j * 5 + 2], y2 = P[j * 5 + 3];
    float s = P[j * 5 + 4];
    box[j] = make_float4(x1, y1, x2, y2);
    sc[j] = s;
    int g = gti[j];
    gts[j] = g;
    unsigned char a = (g >= 0) ? 1 : 0;
    act[j] = a;
    local_pos += a;
    float pv = 0.f;
    if (g >= 0) {
      float4 gb = make_float4(GB[g * 4], GB[g * 4 + 1], GB[g * 4 + 2], GB[g * 4 + 3]);
      float i2 = iou_box(gb, make_float4(x1, y1, x2, y2));
      pv = -logf(EPSF + i2) * s;
    }
    per[j] = pv;
  }
  if (tid < BG) rec[tid] = -1;
  for (int off = 32; off; off >>= 1) local_pos += __shfl_down(local_pos, off);
  if (lane == 0) rrem[wave] = local_pos;
  __syncthreads();
  int n_pos = 0;
  if (tid == 0) {
    for (int w = 0; w < NW; ++w) n_pos += rrem[w];
    sh_nact = n_pos;
  }
  float pull_sum = 0.f, push_sum = 0.f, pull_cnt = 0.f, push_cnt = 0.f;
  int t0_hasrem = 0;
  __syncthreads();

  while (true) {
    int nact = sh_nact;
    if (nact <= 0) break;
    float bs = -INFINITY;
    int bi = BN;
    for (int k = 0; k < PT; ++k) {
      int j = tid + k * NT;
      if (act[j]) {
        float s = sc[j];
        if (s > bs || (s == bs && j < bi)) { bs = s; bi = j; }
      }
    }
    for (int off = 32; off; off >>= 1) {
      float os = __shfl_down(bs, off);
      int oi = __shfl_down(bi, off);
      if (os > bs || (os == bs && oi < bi)) { bs = os; bi = oi; }
    }
    if (lane == 0) { rs[wave] = bs; ri[wave] = bi; }
    __syncthreads();
    if (tid == 0) {
      float cs = rs[0]; int ci = ri[0];
      for (int w = 1; w < NW; ++w)
        if (rs[w] > cs || (rs[w] == cs && ri[w] < ci)) { cs = rs[w]; ci = ri[w]; }
      int i = ci;
      int ig = gts[i];
      act[i] = 0;
      t0_hasrem = (nact - 1 > 0);
      int r = rec[ig];
      if (r >= 0) {
        pull_cnt += 1.f;
        if (t0_hasrem) {
          float i2 = iou_box(box[r], box[i]);
          float m = fmaxf(i2, EPSF);
          pull_sum += -logf(1.f - THR + m) * sc[i];
        }
      } else {
        rec[ig] = i;
      }
      sh_ig = ig; sh_ibox = box[i];
    }
    __syncthreads();
    float4 ib = sh_ibox;
    int igx = sh_ig;
    int removed = 0, qcc = 0, anyp = 0;
    float qss = 0.f;
    for (int k = 0; k < PT; ++k) {
      int j = tid + k * NT;
      if (act[j]) {
        float i2 = iou_box(ib, box[j]);
        if (i2 > THR) {
          act[j] = 0;
          removed++;
          int gj = gts[j];
          if (gj != igx) {
            anyp = 1;
            if (rec[gj] < 0) { qcc++; qss += per[j]; }
          }
        }
      }
    }
    for (int off = 32; off; off >>= 1) {
      removed += __shfl_down(removed, off);
      qcc += __shfl_down(qcc, off);
      qss += __shfl_down(qss, off);
      anyp |= __shfl_down(anyp, off);
    }
    if (lane == 0) { rrem[wave] = removed; rqc[wave] = qcc; rqs[wave] = qss; rany[wave] = anyp; }
    __syncthreads();
    if (tid == 0) {
      int rm = 0, qct = 0, ap = 0; float qst = 0.f;
      for (int w = 0; w < NW; ++w) { rm += rrem[w]; qct += rqc[w]; qst += rqs[w]; ap |= rany[w]; }
      sh_nact = nact - 1 - rm;
      if (t0_hasrem && ap) {
        push_sum += qst / ((float)qct + EPSF);
        push_cnt += 1.f;
      }
    }
    __syncthreads();
  }

  if (tid == 0) {
    float gate = (n_pos > 1) ? 1.f : 0.f;
    out_bp[b * 2 + 0] = gate * push_sum / (push_cnt + EPSF);
    out_bp[b * 2 + 1] = gate * pull_sum / (pull_cnt + EPSF);
  }
}

// ============================================================== launch =====
extern "C" void kernel_launch(void* const* d_in, const int* in_sizes, int n_in,
                              void* d_out, int out_size, void* d_ws, size_t ws_size,
                              hipStream_t stream) {
  const int* gti = (const int*)d_in[1];
  const float* gtb = (const float*)d_in[2];
  const float* props = (const float*)d_in[3];
  float* out = (float*)d_out;
  const int nb = in_sizes[1] / BN;   // 8

  // ws layout (bytes)
  const size_t off_adj  = 0;                                   // nb*2048*64 u32
  const size_t off_box  = off_adj  + (size_t)nb * BN * 64 * 4;
  const size_t off_per  = off_box  + (size_t)nb * BN * 16;
  const size_t off_sc   = off_per  + (size_t)nb * BN * 4;
  const size_t off_actw = off_sc   + (size_t)nb * BN * 4;
  const size_t off_bp   = off_actw + (size_t)nb * 64 * 4;
  const size_t off_gts  = off_bp   + (size_t)nb * 2 * 4;
  const size_t needed   = off_gts  + (size_t)nb * BN * 2;

  if (ws_size >= needed) {
    char* ws = (char*)d_ws;
    unsigned* adj = (unsigned*)(ws + off_adj);
    float4* boxs = (float4*)(ws + off_box);
    float* pers = (float*)(ws + off_per);
    float* scs = (float*)(ws + off_sc);
    unsigned* actw = (unsigned*)(ws + off_actw);
    float* bp = (float*)(ws + off_bp);
    short* gtss = (short*)(ws + off_gts);

    k1_sort<<<nb, 256, 0, stream>>>(gti, gtb, props, boxs, pers, gtss, scs, actw);
    k2_adj<<<nb * 32, 256, 0, stream>>>(boxs, adj);
    k3_resolve_loss<<<nb, 256, 0, stream>>>(boxs, pers, gtss, scs, actw, adj, bp);
    nms_finalize_kernel<<<1, 64, 0, stream>>>(bp, out, nb);
  } else {
    float* bp = (float*)d_ws;
    nms_loss_kernel<<<nb, NT, 0, stream>>>(gti, gtb, props, bp);
    nms_finalize_kernel<<<1, 64, 0, stream>>>(bp, out, nb);
  }
}

// Round 4
// 124.491 us; speedup vs baseline: 6.6251x; 1.3022x over previous
//
#include <hip/hip_runtime.h>
#include <math.h>
#include <limits.h>

#define EPSF 1e-6f
#define THR 0.5f
#define PUSH_W 1.0f
#define PULL_W 1.0f

constexpr int BN = 2048;    // proposals per batch
constexpr int BG = 64;      // gt boxes per batch

__device__ __forceinline__ float iou_box(float4 a, float4 b) {
  float aa = (a.z - a.x) * (a.w - a.y);
  float ab = (b.z - b.x) * (b.w - b.y);
  float w = fmaxf(fminf(a.z, b.z) - fmaxf(a.x, b.x), 0.f);
  float h = fmaxf(fminf(a.w, b.w) - fmaxf(a.y, b.y), 0.f);
  float inter = w * h;
  return inter / (aa + ab - inter + EPSF);
}

// -------------------------------------------------- K1: rank-by-count sort
// grid = nb*8, blk%8 = batch (XCD-local writes). Each block ranks 256 rows
// against all 2048 keys staged in LDS (broadcast reads, no barriers in loop).
__global__ __launch_bounds__(256) void k1_sort(
    const int* __restrict__ gti_all, const float* __restrict__ gtb_all,
    const float* __restrict__ prop_all,
    float4* __restrict__ boxs, float* __restrict__ pers,
    short* __restrict__ gtss, float* __restrict__ scs)
{
  const int b = blockIdx.x & 7;        // batch -> XCD
  const int rg = blockIdx.x >> 3;      // row group
  const int tid = threadIdx.x;
  __shared__ unsigned long long key[BN];   // 16 KB

  const float* P = prop_all + (size_t)b * BN * 5;
  const int* gti = gti_all + b * BN;
  const float* GB = gtb_all + b * BG * 4;

  for (int k = 0; k < 8; ++k) {
    int j = tid + k * 256;
    unsigned bits = __float_as_uint(P[j * 5 + 4]);
    key[j] = ((unsigned long long)bits << 32) | (unsigned)(BN - 1 - j);
  }
  __syncthreads();

  const int r = rg * 256 + tid;        // my row (pre-sort index r maps via key)
  const unsigned long long myk = key[r];
  int rank = 0;
  const ulonglong2* K2 = (const ulonglong2*)key;
#pragma unroll 8
  for (int j = 0; j < BN / 2; ++j) {
    ulonglong2 kk = K2[j];
    rank += (kk.x > myk) ? 1 : 0;
    rank += (kk.y > myk) ? 1 : 0;
  }

  // emit row r's data at sorted position `rank`
  int idx = (BN - 1) - (int)(myk & 0xffffffffu);
  float x1 = P[idx * 5 + 0], y1 = P[idx * 5 + 1];
  float x2 = P[idx * 5 + 2], y2 = P[idx * 5 + 3];
  float s = __uint_as_float((unsigned)(myk >> 32));
  int g = gti[idx];
  float4 bx = make_float4(x1, y1, x2, y2);
  boxs[b * BN + rank] = bx;
  scs[b * BN + rank] = s;
  gtss[b * BN + rank] = (short)g;
  float pv = 0.f;
  if (g >= 0) {
    float4 gb = make_float4(GB[g * 4 + 0], GB[g * 4 + 1], GB[g * 4 + 2], GB[g * 4 + 3]);
    float i2 = iou_box(gb, bx);
    pv = -logf(EPSF + i2) * s;
  }
  pers[b * BN + rank] = pv;
}

// ------------------------------------------------------------- K2: adjacency
// grid = nb*32, blk%8 = batch so batch-b adj is written from XCD b's CUs.
__global__ __launch_bounds__(256) void k2_adj(
    const float4* __restrict__ boxs, unsigned* __restrict__ adj)
{
  const int b = blockIdx.x & 7;
  const int rg = blockIdx.x >> 3;
  const int tid = threadIdx.x;
  __shared__ float4 bs[BN];     // 32 KB

  const float4* B = boxs + b * BN;
  for (int k = 0; k < 8; ++k) bs[tid + k * 256] = B[tid + k * 256];
  __syncthreads();

  const int row = rg * 64 + (tid >> 2);
  const int q = tid & 3;
  float4 rb = bs[row];
  unsigned* arow = adj + ((size_t)b * BN + row) * 64;
#pragma unroll
  for (int wi = 0; wi < 16; ++wi) {
    int w = q * 16 + wi;
    int j0 = w * 32;
    unsigned bits = 0;
#pragma unroll
    for (int jj = 0; jj < 32; ++jj) {
      float i2 = iou_box(rb, bs[j0 + jj]);
      bits |= (i2 > THR) ? (1u << jj) : 0u;
    }
    arow[w] = bits;
  }
}

// ------------------------------------------- K3: pick-resolve + parallel loss
__global__ __launch_bounds__(256) void k3_resolve_loss(
    const float4* __restrict__ boxs, const float* __restrict__ pers,
    const short* __restrict__ gtss, const float* __restrict__ scs,
    const unsigned* __restrict__ adj, float* __restrict__ out_bp)
{
  const int b = blockIdx.x;            // batch b -> XCD b (matches k1/k2 swizzle)
  const int tid = threadIdx.x;
  const int lane = tid & 63;
  const int wave = tid >> 6;

  __shared__ unsigned short plist[BN];   // pick ranks in order (4 KB)
  __shared__ unsigned pm_s[64];          // pickmask
  __shared__ unsigned pmpre[64];         // prefix popcounts
  __shared__ unsigned aw[64];            // active mask by rank
  __shared__ short gts_s[BN];            // 4 KB
  __shared__ float qs[BN];               // 8 KB
  __shared__ int qc[BN];                 // 8 KB
  __shared__ unsigned hp[64];            // has_push bit per event
  __shared__ int fpr[BG];                // first pick rank per GT
  __shared__ unsigned short ev2rank[BN]; // 4 KB
  __shared__ int Pcnt, lastrem, nposs;
  __shared__ float redp[4][4];

  const unsigned* A = adj + (size_t)b * BN * 64;

  // ---- phase A: init accumulators, stage gts, build active mask ----
  if (tid < 64) { hp[tid] = 0u; fpr[tid] = INT_MAX; aw[tid] = 0u; }
  if (tid == 0) { Pcnt = 0; lastrem = 0; nposs = 0; }
  __syncthreads();
  int myp = 0;
  for (int k = 0; k < 8; ++k) {
    int j = tid + k * 256;
    qs[j] = 0.f; qc[j] = 0;
    short g = gtss[b * BN + j];
    gts_s[j] = g;
    if (g >= 0) { myp++; atomicOr(&aw[j >> 5], 1u << (j & 31)); }
  }
  for (int o = 1; o < 64; o <<= 1) myp += __shfl_xor(myp, o);
  __syncthreads();
  if (lane == 0) atomicAdd(&nposs, myp);
  __syncthreads();

  // ---- phase B: wave0 greedy resolve over 32 chunks of 64 ranks ----
  if (wave == 0) {
    unsigned sup = 0;
    unsigned act = aw[lane];
    unsigned mypm = 0;
    int npick = 0;                 // wave-uniform
    int prevbase = 0, prevcnt = 0;
    uint2 diag = *(const uint2*)&A[(size_t)lane * 64 + 0];   // chunk 0
    for (int c = 0; c < 32; ++c) {
      // prefetch next chunk's symmetric diag block (row lane == col lane)
      uint2 diagn = diag;
      if (c + 1 < 32)
        diagn = *(const uint2*)&A[(size_t)((c + 1) * 64 + lane) * 64 + 2 * (c + 1)];

      // apply previous chunk's picks to sup (16-wide batched loads)
      for (int t = 0; t < prevcnt; t += 16) {
        unsigned r[16];
#pragma unroll
        for (int k = 0; k < 16; ++k) {
          int idx = prevbase + t + k;
          int lim = prevbase + prevcnt - 1;
          if (idx > lim) idx = lim;
          int rank = (int)plist[idx];
          r[k] = A[(size_t)rank * 64 + lane];
        }
        unsigned acc = 0;
#pragma unroll
        for (int k = 0; k < 16; ++k) acc |= r[k];
        sup |= acc;
      }

      // per-lane candidate bit for this chunk
      unsigned as0 = act & ~sup;
      unsigned w0 = (unsigned)__shfl((int)as0, 2 * c);
      unsigned w1 = (unsigned)__shfl((int)as0, 2 * c + 1);
      unsigned mybit = (lane < 32) ? ((w0 >> lane) & 1u) : ((w1 >> (lane - 32)) & 1u);

      unsigned long long myrow = ((unsigned long long)diag.y << 32) | (unsigned long long)diag.x;
      unsigned long long pickword = 0;
      int cbase = npick;
      while (true) {
        unsigned long long bal = __ballot(mybit != 0u);
        if (!bal) break;
        int bpos = (int)__ffsll(bal) - 1;
        pickword |= (1ull << bpos);
        if (lane == 0) plist[npick] = (unsigned short)(c * 64 + bpos);
        npick++;
        mybit &= ~((unsigned)((myrow >> bpos) & 1ull));  // symmetric: row bit == col bit
      }
      if (lane == 2 * c)     mypm |= (unsigned)(pickword & 0xffffffffull);
      if (lane == 2 * c + 1) mypm |= (unsigned)(pickword >> 32);
      prevbase = cbase; prevcnt = npick - cbase;
      diag = diagn;
    }
    pm_s[lane] = mypm;
    if (lane == 0) Pcnt = npick;
  }
  __syncthreads();

  // ---- phase C: prefix popcounts ----
  if (tid < 64) {
    int s = 0;
    for (int w = 0; w < tid; ++w) s += __popc(pm_s[w]);
    pmpre[tid] = (unsigned)s;
  }
  __syncthreads();

  const int P = Pcnt;

  // ---- stage 1: per-box removal event; picks fill ev2rank/fpr ----
  int rpv[8]; int ejv[8];
#pragma unroll
  for (int k = 0; k < 8; ++k) {
    int j = tid + (k << 8);
    const uint4* R = (const uint4*)(A + (size_t)j * 64);
    int frank = -1;
#pragma unroll
    for (int q = 0; q < 16; ++q) {
      uint4 r4 = R[q];
      unsigned m0 = r4.x & pm_s[q * 4 + 0];
      unsigned m1 = r4.y & pm_s[q * 4 + 1];
      unsigned m2 = r4.z & pm_s[q * 4 + 2];
      unsigned m3 = r4.w & pm_s[q * 4 + 3];
      if (frank < 0 && m0) frank = q * 128 +  0 + __ffs(m0) - 1;
      if (frank < 0 && m1) frank = q * 128 + 32 + __ffs(m1) - 1;
      if (frank < 0 && m2) frank = q * 128 + 64 + __ffs(m2) - 1;
      if (frank < 0 && m3) frank = q * 128 + 96 + __ffs(m3) - 1;
    }
    int e = -1;
    if (frank >= 0)
      e = (int)pmpre[frank >> 5] + __popc(pm_s[frank >> 5] & ((1u << (frank & 31)) - 1u));
    rpv[k] = frank; ejv[k] = e;
    if (frank == j) {                       // j is a pick
      ev2rank[e] = (unsigned short)j;
      atomicMin(&fpr[(int)gts_s[j]], j);
      rpv[k] = -1;                          // no removal contribution
    }
  }
  __syncthreads();

  // ---- stage 2: non-pick removal contributions (fpr now final) ----
#pragma unroll
  for (int k = 0; k < 8; ++k) {
    int j = tid + (k << 8);
    int frank = rpv[k];
    if (frank < 0) continue;
    int gj = (int)gts_s[j];
    if (gj < 0) continue;                   // never active
    int e = ejv[k];
    if (e == P - 1) atomicOr(&lastrem, 1);
    int gt = (int)gts_s[frank];
    if (gj != gt) {
      atomicOr(&hp[e >> 5], 1u << (e & 31));
      if (fpr[gj] > frank) {                // unseen at event e
        atomicAdd(&qs[e], pers[b * BN + j]);
        atomicAdd(&qc[e], 1);
      }
    }
  }
  __syncthreads();

  // ---- event pass: pull/push per event, block reduce ----
  float pull_l = 0.f, pcl = 0.f, push_l = 0.f, pshl = 0.f;
  for (int t = tid; t < P; t += 256) {
    int r = (int)ev2rank[t];
    int g = (int)gts_s[r];
    bool seen = (fpr[g] < r);
    bool hr = (t < P - 1) || (lastrem != 0);
    if (seen) {
      pcl += 1.f;
      if (hr) {
        float4 bA = boxs[b * BN + fpr[g]];
        float4 bB = boxs[b * BN + r];
        float io = iou_box(bA, bB);
        pull_l += -logf(1.f - THR + fmaxf(io, EPSF)) * scs[b * BN + r];
      }
    }
    if (hr && ((hp[t >> 5] >> (t & 31)) & 1u)) {
      pshl += 1.f;
      push_l += qs[t] / ((float)qc[t] + EPSF);
    }
  }
  for (int o = 1; o < 64; o <<= 1) {
    pull_l += __shfl_xor(pull_l, o);
    pcl    += __shfl_xor(pcl, o);
    push_l += __shfl_xor(push_l, o);
    pshl   += __shfl_xor(pshl, o);
  }
  if (lane == 0) { redp[wave][0] = pull_l; redp[wave][1] = pcl; redp[wave][2] = push_l; redp[wave][3] = pshl; }
  __syncthreads();
  if (tid == 0) {
    float Ps = 0.f, Pc = 0.f, Ss = 0.f, Sc = 0.f;
    for (int w = 0; w < 4; ++w) { Ps += redp[w][0]; Pc += redp[w][1]; Ss += redp[w][2]; Sc += redp[w][3]; }
    float gate = (nposs > 1) ? 1.f : 0.f;
    out_bp[b * 2 + 0] = gate * Ss / (Sc + EPSF);   // push
    out_bp[b * 2 + 1] = gate * Ps / (Pc + EPSF);   // pull
  }
}

__global__ void nms_finalize_kernel(const float* __restrict__ bp, float* __restrict__ out, int nb) {
  if (threadIdx.x == 0 && blockIdx.x == 0) {
    float ps = 0.f, pl = 0.f;
    for (int b = 0; b < nb; ++b) { ps += bp[2 * b]; pl += bp[2 * b + 1]; }
    float inv = 1.f / (float)nb;
    out[0] = ps * inv * PUSH_W;
    out[1] = pl * inv * PULL_W;
  }
}

// =============================== fallback path (round-1 kernel, proven) =====
constexpr int NT = 256;
constexpr int PT = BN / NT;
constexpr int NW = NT / 64;

__global__ __launch_bounds__(NT) void nms_loss_kernel(
    const int* __restrict__ gti_all, const float* __restrict__ gtb_all,
    const float* __restrict__ prop_all, float* __restrict__ out_bp)
{
  const int b = blockIdx.x;
  const int tid = threadIdx.x;
  const int lane = tid & 63;
  const int wave = tid >> 6;

  __shared__ float4 box[BN];
  __shared__ float sc[BN];
  __shared__ float per[BN];
  __shared__ int gts[BN];
  __shared__ unsigned char act[BN];
  __shared__ int rec[BG];
  __shared__ float rs[NW];
  __shared__ int ri[NW];
  __shared__ int rrem[NW];
  __shared__ int rqc[NW];
  __shared__ float rqs[NW];
  __shared__ int rany[NW];
  __shared__ int sh_nact;
  __shared__ int sh_ig;
  __shared__ float4 sh_ibox;

  const int* gti = gti_all + b * BN;
  const float* GB = gtb_all + b * BG * 4;
  const float* P = prop_all + (size_t)b * BN * 5;

  int local_pos = 0;
  for (int k = 0; k < PT; ++k) {
    int j = tid + k * NT;
    float x1 = P[j * 5 + 0], y1 = P[j * 5 + 1];
    float x2 = P[j * 5 + 2], y2 = P[j * 5 + 3];
    float s = P[j * 5 + 4];
    box[j] = make_float4(x1, y1, x2, y2);
    sc[j] = s;
    int g = gti[j];
    gts[j] = g;
    unsigned char a = (g >= 0) ? 1 : 0;
    act[j] = a;
    local_pos += a;
    float pv = 0.f;
    if (g >= 0) {
      float4 gb = make_float4(GB[g * 4], GB[g * 4 + 1], GB[g * 4 + 2], GB[g * 4 + 3]);
      float i2 = iou_box(gb, make_float4(x1, y1, x2, y2));
      pv = -logf(EPSF + i2) * s;
    }
    per[j] = pv;
  }
  if (tid < BG) rec[tid] = -1;
  for (int off = 32; off; off >>= 1) local_pos += __shfl_down(local_pos, off);
  if (lane == 0) rrem[wave] = local_pos;
  __syncthreads();
  int n_pos = 0;
  if (tid == 0) {
    for (int w = 0; w < NW; ++w) n_pos += rrem[w];
    sh_nact = n_pos;
  }
  float pull_sum = 0.f, push_sum = 0.f, pull_cnt = 0.f, push_cnt = 0.f;
  int t0_hasrem = 0;
  __syncthreads();

  while (true) {
    int nact = sh_nact;
    if (nact <= 0) break;
    float bs = -INFINITY;
    int bi = BN;
    for (int k = 0; k < PT; ++k) {
      int j = tid + k * NT;
      if (act[j]) {
        float s = sc[j];
        if (s > bs || (s == bs && j < bi)) { bs = s; bi = j; }
      }
    }
    for (int off = 32; off; off >>= 1) {
      float os = __shfl_down(bs, off);
      int oi = __shfl_down(bi, off);
      if (os > bs || (os == bs && oi < bi)) { bs = os; bi = oi; }
    }
    if (lane == 0) { rs[wave] = bs; ri[wave] = bi; }
    __syncthreads();
    if (tid == 0) {
      float cs = rs[0]; int ci = ri[0];
      for (int w = 1; w < NW; ++w)
        if (rs[w] > cs || (rs[w] == cs && ri[w] < ci)) { cs = rs[w]; ci = ri[w]; }
      int i = ci;
      int ig = gts[i];
      act[i] = 0;
      t0_hasrem = (nact - 1 > 0);
      int r = rec[ig];
      if (r >= 0) {
        pull_cnt += 1.f;
        if (t0_hasrem) {
          float i2 = iou_box(box[r], box[i]);
          float m = fmaxf(i2, EPSF);
          pull_sum += -logf(1.f - THR + m) * sc[i];
        }
      } else {
        rec[ig] = i;
      }
      sh_ig = ig; sh_ibox = box[i];
    }
    __syncthreads();
    float4 ib = sh_ibox;
    int igx = sh_ig;
    int removed = 0, qcc = 0, anyp = 0;
    float qss = 0.f;
    for (int k = 0; k < PT; ++k) {
      int j = tid + k * NT;
      if (act[j]) {
        float i2 = iou_box(ib, box[j]);
        if (i2 > THR) {
          act[j] = 0;
          removed++;
          int gj = gts[j];
          if (gj != igx) {
            anyp = 1;
            if (rec[gj] < 0) { qcc++; qss += per[j]; }
          }
        }
      }
    }
    for (int off = 32; off; off >>= 1) {
      removed += __shfl_down(removed, off);
      qcc += __shfl_down(qcc, off);
      qss += __shfl_down(qss, off);
      anyp |= __shfl_down(anyp, off);
    }
    if (lane == 0) { rrem[wave] = removed; rqc[wave] = qcc; rqs[wave] = qss; rany[wave] = anyp; }
    __syncthreads();
    if (tid == 0) {
      int rm = 0, qct = 0, ap = 0; float qst = 0.f;
      for (int w = 0; w < NW; ++w) { rm += rrem[w]; qct += rqc[w]; qst += rqs[w]; ap |= rany[w]; }
      sh_nact = nact - 1 - rm;
      if (t0_hasrem && ap) {
        push_sum += qst / ((float)qct + EPSF);
        push_cnt += 1.f;
      }
    }
    __syncthreads();
  }

  if (tid == 0) {
    float gate = (n_pos > 1) ? 1.f : 0.f;
    out_bp[b * 2 + 0] = gate * push_sum / (push_cnt + EPSF);
    out_bp[b * 2 + 1] = gate * pull_sum / (pull_cnt + EPSF);
  }
}

// ============================================================== launch =====
extern "C" void kernel_launch(void* const* d_in, const int* in_sizes, int n_in,
                              void* d_out, int out_size, void* d_ws, size_t ws_size,
                              hipStream_t stream) {
  const int* gti = (const int*)d_in[1];
  const float* gtb = (const float*)d_in[2];
  const float* props = (const float*)d_in[3];
  float* out = (float*)d_out;
  const int nb = in_sizes[1] / BN;   // 8

  // ws layout (bytes)
  const size_t off_adj  = 0;                                   // nb*2048*64 u32
  const size_t off_box  = off_adj  + (size_t)nb * BN * 64 * 4;
  const size_t off_per  = off_box  + (size_t)nb * BN * 16;
  const size_t off_sc   = off_per  + (size_t)nb * BN * 4;
  const size_t off_bp   = off_sc   + (size_t)nb * BN * 4;
  const size_t off_gts  = off_bp   + (size_t)nb * 2 * 4;
  const size_t needed   = off_gts  + (size_t)nb * BN * 2;

  if (ws_size >= needed && nb == 8) {
    char* ws = (char*)d_ws;
    unsigned* adj = (unsigned*)(ws + off_adj);
    float4* boxs = (float4*)(ws + off_box);
    float* pers = (float*)(ws + off_per);
    float* scs = (float*)(ws + off_sc);
    float* bp = (float*)(ws + off_bp);
    short* gtss = (short*)(ws + off_gts);

    k1_sort<<<nb * 8, 256, 0, stream>>>(gti, gtb, props, boxs, pers, gtss, scs);
    k2_adj<<<nb * 32, 256, 0, stream>>>(boxs, adj);
    k3_resolve_loss<<<nb, 256, 0, stream>>>(boxs, pers, gtss, scs, adj, bp);
    nms_finalize_kernel<<<1, 64, 0, stream>>>(bp, out, nb);
  } else {
    float* bp = (float*)d_ws;
    nms_loss_kernel<<<nb, NT, 0, stream>>>(gti, gtb, props, bp);
    nms_finalize_kernel<<<1, 64, 0, stream>>>(bp, out, nb);
  }
}